// Round 4
// baseline (207.179 us; speedup 1.0000x reference)
//
#include <hip/hip_runtime.h>
#include <math.h>

// ProjectionLayer: out[b,t,gx,gy] = data[b,t, argmin_n ||locs[b,n]*25+25 - (gx,gy)|| ]
// B=64, T=1024, N=256 sensors, G=50 (2500 grid cells).
// Stage 1 (nearest_k): 41M distance evals -> nearest[b,g] in d_ws (640 KB).
// Stage 2 (gather_lds_k): register-prefetch next 8 rows while gathering current
// 8 rows from LDS (ds_read_b32 scatter ~2-way alias, cheap), 655 MB coalesced
// NT float4 stores. HBM-write-bound, roofline ~110-125 us.
// R1 lesson: per-lane scattered GLOBAL loads ~1 lane/cycle in TA -> use LDS.
// R2 lesson: 4 blocks/CU left store queue underfed + staging latency exposed;
//            now 2048 blocks (8/CU, 32 waves) + T14 reg-prefetch.
// R3 lesson: __builtin_nontemporal_store needs a NATIVE clang vector type,
//            not HIP_vector_type -> use ext_vector_type(4) float.

#define GRIDG  50
#define GG     2500   // GRIDG*GRIDG
#define GQ     625    // GG/4 (float4 groups per output row)
#define NS     256    // sensors
#define TT     1024
#define BB     64
#define TCHUNK 32     // t rows per block
#define RSTG   8      // rows staged in LDS per barrier (8 KB)
#define NCH    (TCHUNK / RSTG)

typedef float f32x4 __attribute__((ext_vector_type(4)));

// exact replication of reference fp32 arithmetic: unfused mul/add + rounded sqrt
__device__ __forceinline__ float ref_dist(float lx, float ly, float gx, float gy) {
    const float dx = lx - gx;
    const float dy = ly - gy;
    const float s  = __fadd_rn(__fmul_rn(dx, dx), __fmul_rn(dy, dy));
    return __fsqrt_rn(s);
}

// ---- Stage 1: nearest sensor index per grid cell -----------------------------
__global__ __launch_bounds__(256) void nearest_k(const float* __restrict__ locs,
                                                 int* __restrict__ nearest) {
    __shared__ float lsx[NS];
    __shared__ float lsy[NS];
    const int b   = blockIdx.x / 10;   // 10 blocks of 256 cover 2500 cells
    const int gc  = blockIdx.x % 10;
    const int tid = threadIdx.x;

    const float2 l = ((const float2*)locs)[b * NS + tid];
    lsx[tid] = __fadd_rn(__fmul_rn(l.x, 25.0f), 25.0f);
    lsy[tid] = __fadd_rn(__fmul_rn(l.y, 25.0f), 25.0f);
    __syncthreads();

    const int g = gc * 256 + tid;
    if (g >= GG) return;
    const float gx = (float)(g / GRIDG);
    const float gy = (float)(g % GRIDG);

    float best = 1.0e30f;
    int   bi   = 0;
    #pragma unroll 4
    for (int n = 0; n < NS; ++n) {          // ascending n + strict '<'  => first-index
        const float d = ref_dist(lsx[n], lsy[n], gx, gy);   //    tie-break == jnp.argmin
        if (d < best) { best = d; bi = n; }
    }
    nearest[b * GG + g] = bi;
}

// ---- Stage 2: LDS-staged broadcast-gather with register prefetch ------------
__global__ __launch_bounds__(256) void gather_lds_k(const float* __restrict__ data,
                                                    const int* __restrict__ nearest,
                                                    float* __restrict__ out) {
    __shared__ float rows[RSTG * NS];   // 8 KB -> occupancy wave-capped, not LDS-capped
    const int tid = threadIdx.x;
    const int b   = blockIdx.y;
    const int t0  = blockIdx.x * TCHUNK;

    // per-thread gather indices (loop-invariant over t) -> registers
    int4 iv[3];
    #pragma unroll
    for (int j = 0; j < 3; ++j) {
        const int gq = tid + j * 256;
        iv[j] = (gq < GQ) ? ((const int4*)nearest)[b * GQ + gq]
                          : make_int4(0, 0, 0, 0);
    }

    const float4* __restrict__ dbase = (const float4*)data + (size_t)b * TT * (NS / 4);
    f32x4*        __restrict__ obase = (f32x4*)out + (size_t)b * TT * GQ;

    // prologue prefetch: chunk 0 (8 rows = 512 float4 = 2/thread, coalesced)
    const float4* __restrict__ src = dbase + (size_t)t0 * (NS / 4);
    float4 pr0 = src[tid];
    float4 pr1 = src[tid + 256];

    for (int c = 0; c < NCH; ++c) {
        // commit prefetched chunk to LDS (vmcnt wait lands here, hidden under
        // previous chunk's gather work)
        ((float4*)rows)[tid]       = pr0;
        ((float4*)rows)[tid + 256] = pr1;
        // issue next chunk's loads before the barrier (T14 issue-early)
        if (c + 1 < NCH) {
            src += RSTG * (NS / 4);
            pr0 = src[tid];
            pr1 = src[tid + 256];
        }
        __syncthreads();

        const int ts = t0 + c * RSTG;
        #pragma unroll
        for (int r = 0; r < RSTG; ++r) {
            const float* __restrict__ row  = rows + r * NS;
            f32x4*       __restrict__ orow = obase + (size_t)(ts + r) * GQ;
            #pragma unroll
            for (int j = 0; j < 3; ++j) {
                const int gq = tid + j * 256;
                if (gq < GQ) {
                    f32x4 v;
                    v.x = row[iv[j].x];
                    v.y = row[iv[j].y];
                    v.z = row[iv[j].z];
                    v.w = row[iv[j].w];
                    __builtin_nontemporal_store(v, &orow[gq]);  // out never re-read
                }
            }
        }
        __syncthreads();   // all waves done reading before next ds_write
    }
}

// ---- Fallback: fused (only if ws too small for the 640 KB index buffer) -----
__global__ __launch_bounds__(256) void fused_k(const float* __restrict__ data,
                                               const float* __restrict__ locs,
                                               float* __restrict__ out) {
    __shared__ float lsx[NS];
    __shared__ float lsy[NS];
    const int b   = blockIdx.z;
    const int tid = threadIdx.x;
    const float2 l = ((const float2*)locs)[b * NS + tid];
    lsx[tid] = __fadd_rn(__fmul_rn(l.x, 25.0f), 25.0f);
    lsy[tid] = __fadd_rn(__fmul_rn(l.y, 25.0f), 25.0f);
    __syncthreads();

    const int gq = blockIdx.x * 256 + tid;
    if (gq >= GQ) return;

    int iv[4];
    #pragma unroll
    for (int k = 0; k < 4; ++k) {
        const int g  = gq * 4 + k;
        const float gx = (float)(g / GRIDG);
        const float gy = (float)(g % GRIDG);
        float best = 1.0e30f;
        int   bi   = 0;
        for (int n = 0; n < NS; ++n) {
            const float d = ref_dist(lsx[n], lsy[n], gx, gy);
            if (d < best) { best = d; bi = n; }
        }
        iv[k] = bi;
    }

    const int t0 = blockIdx.y * (TT / 2);
    const float* __restrict__ dbase = data + (size_t)b * TT * NS;
    float4*      __restrict__ obase = (float4*)out + (size_t)b * TT * GQ + gq;
    #pragma unroll 4
    for (int t = t0; t < t0 + TT / 2; ++t) {
        const float* __restrict__ row = dbase + t * NS;
        float4 v;
        v.x = row[iv[0]];
        v.y = row[iv[1]];
        v.z = row[iv[2]];
        v.w = row[iv[3]];
        obase[(size_t)t * GQ] = v;
    }
}

extern "C" void kernel_launch(void* const* d_in, const int* in_sizes, int n_in,
                              void* d_out, int out_size, void* d_ws, size_t ws_size,
                              hipStream_t stream) {
    const float* data = (const float*)d_in[0];   // [64,1024,256] f32
    const float* locs = (const float*)d_in[1];   // [64,256,2]    f32
    float*       out  = (float*)d_out;           // [64,1024,50,50] f32
    (void)in_sizes; (void)n_in; (void)out_size;

    const size_t idx_bytes = (size_t)BB * GG * sizeof(int);   // 640 KB
    if (ws_size >= idx_bytes) {
        int* nearest = (int*)d_ws;
        nearest_k<<<dim3(BB * 10), 256, 0, stream>>>(locs, nearest);
        gather_lds_k<<<dim3(TT / TCHUNK, BB), 256, 0, stream>>>(data, nearest, out);
    } else {
        fused_k<<<dim3(3, 2, BB), 256, 0, stream>>>(data, locs, out);
    }
}